// Round 1
// baseline (208.459 us; speedup 1.0000x reference)
//
#include <hip/hip_runtime.h>
#include <hip/hip_bf16.h>

#define S_LEN 2048
#define NH 16
#define DKH 64
#define DM 1024
#define QK_SCALE 0.125f

typedef __attribute__((ext_vector_type(8))) short bf16x8;
typedef __attribute__((ext_vector_type(4))) float f32x4;
typedef __attribute__((ext_vector_type(4))) unsigned int u32x4;

__device__ __forceinline__ unsigned short f2bf(float f) {
  unsigned int x = __builtin_bit_cast(unsigned int, f);
  x += 0x7fffu + ((x >> 16) & 1u);   // RNE
  return (unsigned short)(x >> 16);
}

__device__ __forceinline__ void gload_lds16(const void* g, void* l) {
  __builtin_amdgcn_global_load_lds(
      (const __attribute__((address_space(1))) unsigned int*)g,
      (__attribute__((address_space(3))) unsigned int*)l, 16, 0, 0);
}

// ---------------- fp32 -> bf16 conversion (memory-bound pre-pass) -----------
__global__ void cvt_f32_to_bf16(const float* __restrict__ in,
                                unsigned short* __restrict__ out, int n) {
  int i = (blockIdx.x * blockDim.x + threadIdx.x) * 8;
  if (i >= n) return;
  float4 a = *(const float4*)(in + i);
  float4 b = *(const float4*)(in + i + 4);
  union { unsigned short us[8]; u32x4 v; } r;
  r.us[0] = f2bf(a.x); r.us[1] = f2bf(a.y); r.us[2] = f2bf(a.z); r.us[3] = f2bf(a.w);
  r.us[4] = f2bf(b.x); r.us[5] = f2bf(b.y); r.us[6] = f2bf(b.z); r.us[7] = f2bf(b.w);
  *(u32x4*)(out + i) = r.v;
}

// ---------------- 128x128 bf16 GEMM, C = A * B^T (m97 structure) ------------
// MODE 0: QKV epilogue -> scatter q,k to [B,H,S,Dk] bf16, v to [B,H,Dk,S] bf16
// MODE 1: proj epilogue -> fp32 C + bias to d_out
template<int MODE>
__global__ __launch_bounds__(256) void gemm_bt(
    const unsigned short* __restrict__ A,   // [M,K] bf16 row-major
    const unsigned short* __restrict__ Bt,  // [N,K] bf16 row-major
    const float* __restrict__ bias,         // [N]
    float* __restrict__ Cf,                 // MODE 1
    unsigned short* __restrict__ qo,        // MODE 0
    unsigned short* __restrict__ ko,
    unsigned short* __restrict__ vto,
    int M, int N, int K)
{
  __shared__ __align__(16) char Asm[128 * 128];   // 128 rows x 64 bf16 (128B/row)
  __shared__ __align__(16) char Bsm[128 * 128];
  int t = threadIdx.x;
  int lane = t & 63, wid = t >> 6;
  int wr = wid >> 1, wc = wid & 1;
  int m0 = blockIdx.y << 7, n0 = blockIdx.x << 7;
  int gi = lane >> 4, c0 = lane & 15;
  int rs = t >> 3, uP = t & 7;

  f32x4 acc[4][4];
#pragma unroll
  for (int i = 0; i < 4; ++i)
#pragma unroll
    for (int j = 0; j < 4; ++j) acc[i][j] = (f32x4){0.f, 0.f, 0.f, 0.f};

  for (int kt = 0; kt < K; kt += 64) {
    // stage A,B tiles: linear LDS dest, inverse-swizzled global source (rule 21)
#pragma unroll
    for (int it = 0; it < 4; ++it) {
      int r = rs + it * 32;
      int c8 = uP ^ (r & 7);
      gload_lds16(A  + ((size_t)(m0 + r) * K + kt + c8 * 8), Asm + r * 128 + uP * 16);
      gload_lds16(Bt + ((size_t)(n0 + r) * K + kt + c8 * 8), Bsm + r * 128 + uP * 16);
    }
    __syncthreads();
#pragma unroll
    for (int kk = 0; kk < 2; ++kk) {
      bf16x8 af[4], bfr[4];
      int uL = kk * 4 + gi;
#pragma unroll
      for (int i = 0; i < 4; ++i) {
        int ra = wr * 64 + i * 16 + c0;
        af[i] = *(const bf16x8*)(Asm + ra * 128 + ((uL ^ (ra & 7)) * 16));
        int rb = wc * 64 + i * 16 + c0;
        bfr[i] = *(const bf16x8*)(Bsm + rb * 128 + ((uL ^ (rb & 7)) * 16));
      }
#pragma unroll
      for (int i = 0; i < 4; ++i)
#pragma unroll
        for (int j = 0; j < 4; ++j)
          acc[i][j] = __builtin_amdgcn_mfma_f32_16x16x32_bf16(af[i], bfr[j], acc[i][j], 0, 0, 0);
    }
    __syncthreads();
  }

  // epilogue: C/D layout col = lane&15, row = (lane>>4)*4 + reg
#pragma unroll
  for (int i = 0; i < 4; ++i) {
#pragma unroll
    for (int j = 0; j < 4; ++j) {
#pragma unroll
      for (int rI = 0; rI < 4; ++rI) {
        int m = m0 + wr * 64 + i * 16 + gi * 4 + rI;
        int n = n0 + wc * 64 + j * 16 + c0;
        float v = acc[i][j][rI] + bias[n];
        if (MODE == 1) {
          Cf[(size_t)m * N + n] = v;
        } else {
          int b = m >> 11, s = m & 2047;
          int which = n >> 10, w2 = n & 1023;
          int h = w2 >> 6, dk = w2 & 63;
          unsigned short bv = f2bf(v);
          size_t hoff = (size_t)(b * NH + h);
          if (which == 0)      qo[(hoff * S_LEN + s) * DKH + dk] = bv;
          else if (which == 1) ko[(hoff * S_LEN + s) * DKH + dk] = bv;
          else                 vto[(hoff * DKH + dk) * S_LEN + s] = bv;  // V transposed
        }
      }
    }
  }
}

// ---------------- flash attention, causal, 4 waves x 16 q-rows --------------
__global__ __launch_bounds__(256) void attn_fwd(
    const unsigned short* __restrict__ Q,   // [BH, S, 64] bf16
    const unsigned short* __restrict__ Kb,  // [BH, S, 64] bf16
    const unsigned short* __restrict__ Vt,  // [BH, 64, S] bf16
    unsigned short* __restrict__ Out)       // [B*S, 1024] bf16
{
  __shared__ __align__(16) char kbuf[64 * 128];
  __shared__ __align__(16) char vbuf[64 * 128];
  __shared__ __align__(16) unsigned short pbuf[4][16][88];  // 176B rows: 16B-aligned, 2-way banks
  int t = threadIdx.x;
  int lane = t & 63, wid = t >> 6;
  int gi = lane >> 4, c0 = lane & 15;
  int qt = blockIdx.x, bh = blockIdx.y;
  int q0 = qt << 6;
  const unsigned short* Qh = Q  + (size_t)bh * S_LEN * DKH;
  const unsigned short* Kh = Kb + (size_t)bh * S_LEN * DKH;
  const unsigned short* Vh = Vt + (size_t)bh * DKH * S_LEN;

  // Q fragments (A-operand): lane holds row l&15, k-chunk (l>>4)*8
  bf16x8 qf[2];
  {
    int qrow = q0 + wid * 16 + c0;
#pragma unroll
    for (int ks = 0; ks < 2; ++ks)
      qf[ks] = *(const bf16x8*)(Qh + (size_t)qrow * DKH + ks * 32 + gi * 8);
  }

  float mrow[4], lrow[4];
  f32x4 o[4];
#pragma unroll
  for (int i = 0; i < 4; ++i) { mrow[i] = -1e30f; lrow[i] = 0.f; o[i] = (f32x4){0, 0, 0, 0}; }

  int rs = t >> 3, uP = t & 7;
  int nt = qt + 1;
  for (int tile = 0; tile < nt; ++tile) {
    int kv0 = tile << 6;
#pragma unroll
    for (int it = 0; it < 2; ++it) {
      int r = rs + it * 32;
      int c8 = uP ^ (r & 7);
      gload_lds16(Kh + ((size_t)(kv0 + r) * DKH + c8 * 8), kbuf + r * 128 + uP * 16);
      gload_lds16(Vh + ((size_t)r * S_LEN + kv0 + c8 * 8), vbuf + r * 128 + uP * 16);
    }
    __syncthreads();

    // S = Q K^T
    f32x4 sc[4];
#pragma unroll
    for (int f = 0; f < 4; ++f) {
      f32x4 s = (f32x4){0, 0, 0, 0};
#pragma unroll
      for (int ks = 0; ks < 2; ++ks) {
        int rb = f * 16 + c0;
        int uL = ks * 4 + gi;
        bf16x8 kf = *(const bf16x8*)(kbuf + rb * 128 + ((uL ^ (rb & 7)) * 16));
        s = __builtin_amdgcn_mfma_f32_16x16x32_bf16(qf[ks], kf, s, 0, 0, 0);
      }
      sc[f] = s;
    }

    // scale + causal mask + tile max
    float tmax[4] = {-1e30f, -1e30f, -1e30f, -1e30f};
    bool diag = (tile == qt);
#pragma unroll
    for (int f = 0; f < 4; ++f) {
#pragma unroll
      for (int i = 0; i < 4; ++i) {
        float v = sc[f][i] * QK_SCALE;
        if (diag && (f * 16 + c0 > wid * 16 + gi * 4 + i)) v = -1e30f;
        sc[f][i] = v;
        tmax[i] = fmaxf(tmax[i], v);
      }
    }
#pragma unroll
    for (int i = 0; i < 4; ++i) {
      float v = tmax[i];
      v = fmaxf(v, __shfl_xor(v, 1));
      v = fmaxf(v, __shfl_xor(v, 2));
      v = fmaxf(v, __shfl_xor(v, 4));
      v = fmaxf(v, __shfl_xor(v, 8));
      tmax[i] = v;
    }
    float alpha[4];
#pragma unroll
    for (int i = 0; i < 4; ++i) {
      float mnew = fmaxf(mrow[i], tmax[i]);
      alpha[i] = __expf(mrow[i] - mnew);
      mrow[i] = mnew;
    }
    float psum[4] = {0, 0, 0, 0};
#pragma unroll
    for (int f = 0; f < 4; ++f)
#pragma unroll
      for (int i = 0; i < 4; ++i) {
        float p = __expf(sc[f][i] - mrow[i]);
        sc[f][i] = p;
        psum[i] += p;
      }
#pragma unroll
    for (int i = 0; i < 4; ++i) {
      float v = psum[i];
      v += __shfl_xor(v, 1);
      v += __shfl_xor(v, 2);
      v += __shfl_xor(v, 4);
      v += __shfl_xor(v, 8);
      lrow[i] = lrow[i] * alpha[i] + v;
    }
#pragma unroll
    for (int df = 0; df < 4; ++df)
#pragma unroll
      for (int i = 0; i < 4; ++i) o[df][i] *= alpha[i];

    // P -> per-wave LDS (bf16), then read back as PV A-fragments
    unsigned short (*pb)[88] = pbuf[wid];
#pragma unroll
    for (int f = 0; f < 4; ++f)
#pragma unroll
      for (int i = 0; i < 4; ++i)
        pb[gi * 4 + i][f * 16 + c0] = f2bf(sc[f][i]);
    asm volatile("s_waitcnt lgkmcnt(0)" ::: "memory");

#pragma unroll
    for (int ks = 0; ks < 2; ++ks) {
      bf16x8 pa = *(const bf16x8*)((const char*)pb + c0 * 176 + (ks * 4 + gi) * 16);
#pragma unroll
      for (int df = 0; df < 4; ++df) {
        int rv = df * 16 + c0;
        int uL = ks * 4 + gi;
        bf16x8 vf = *(const bf16x8*)(vbuf + rv * 128 + ((uL ^ (rv & 7)) * 16));
        o[df] = __builtin_amdgcn_mfma_f32_16x16x32_bf16(pa, vf, o[df], 0, 0, 0);
      }
    }
    __syncthreads();
  }

  // normalize + store attn output [B*S, 1024] bf16
  int b = bh >> 4, h = bh & 15;
#pragma unroll
  for (int i = 0; i < 4; ++i) {
    float rl = 1.0f / lrow[i];
    int row = q0 + wid * 16 + gi * 4 + i;
    size_t base = ((size_t)(b * S_LEN) + row) * DM + h * DKH;
#pragma unroll
    for (int df = 0; df < 4; ++df)
      Out[base + df * 16 + c0] = f2bf(o[df][i] * rl);
  }
}

// ----------------------------------------------------------------------------
extern "C" void kernel_launch(void* const* d_in, const int* in_sizes, int n_in,
                              void* d_out, int out_size, void* d_ws, size_t ws_size,
                              hipStream_t stream) {
  const float* x       = (const float*)d_in[0];
  const float* w_atten = (const float*)d_in[1];
  const float* b_atten = (const float*)d_in[2];
  const float* w_proj  = (const float*)d_in[3];
  const float* b_proj  = (const float*)d_in[4];
  float* out = (float*)d_out;
  char* ws = (char*)d_ws;

  unsigned short* x_bf  = (unsigned short*)(ws);                    // 8 MB
  unsigned short* wa_bf = (unsigned short*)(ws + ((size_t)8  << 20)); // 6 MB
  unsigned short* wp_bf = (unsigned short*)(ws + ((size_t)14 << 20)); // 2 MB
  unsigned short* q_bf  = (unsigned short*)(ws + ((size_t)16 << 20)); // 8 MB
  unsigned short* k_bf  = (unsigned short*)(ws + ((size_t)24 << 20)); // 8 MB
  unsigned short* vt_bf = (unsigned short*)(ws + ((size_t)32 << 20)); // 8 MB
  unsigned short* at_bf = (unsigned short*)(ws + ((size_t)40 << 20)); // 8 MB

  cvt_f32_to_bf16<<<2048, 256, 0, stream>>>(x, x_bf, 4194304);
  cvt_f32_to_bf16<<<1536, 256, 0, stream>>>(w_atten, wa_bf, 3145728);
  cvt_f32_to_bf16<<<512, 256, 0, stream>>>(w_proj, wp_bf, 1048576);

  gemm_bt<0><<<dim3(24, 32), 256, 0, stream>>>(x_bf, wa_bf, b_atten, nullptr,
                                               q_bf, k_bf, vt_bf, 4096, 3072, 1024);
  attn_fwd<<<dim3(32, 32), 256, 0, stream>>>(q_bf, k_bf, vt_bf, at_bf);
  gemm_bt<1><<<dim3(8, 32), 256, 0, stream>>>(at_bf, wp_bf, b_proj, out,
                                              nullptr, nullptr, nullptr, 4096, 1024, 1024);
}